// Round 1
// baseline (288.650 us; speedup 1.0000x reference)
//
#include <hip/hip_runtime.h>
#include <stdint.h>

#define B_   16
#define T_   2048
#define D_   1024
#define TT_  2046
#define W_   682            // MAX_WORDS
#define BW_  (B_ * W_)      // 10912
#define NMUT 64
#define NBIN 32

// K2 heterogeneous-grid section sizes
#define G_WF   BW_          // word-feature blocks
#define G_DW   1024         // dense_w cast blocks (1024*1024 f32 / (256*4))
#define G_OW   64           // out_w cast blocks
#define G_FOLD 32           // W_eff fold blocks
#define G_ZERO 1023         // out zero blocks (10912*96 / 1024)

typedef __attribute__((ext_vector_type(8))) short s8b;    // 8 bf16 (4 VGPRs)
typedef __attribute__((ext_vector_type(4))) float f32x4;

__device__ inline short f2bf(float f) {                   // RNE f32->bf16
    uint32_t u = __builtin_bit_cast(uint32_t, f);
    u += 0x7FFFu + ((u >> 16) & 1u);
    return (short)(u >> 16);
}

__device__ inline float fast_tanh(float x) {
    float xc = fminf(fmaxf(x, -15.f), 15.f);
    float e  = __expf(2.f * xc);
    return 1.f - 2.f / (e + 1.f);
}

__device__ inline void gload_lds16(const void* g, void* l) {
    __builtin_amdgcn_global_load_lds(
        (const __attribute__((address_space(1))) uint32_t*)g,
        (__attribute__((address_space(3))) uint32_t*)l, 16, 0, 0);
}

// ---------------------------------------------------------------------------
// K1: word-boundary scan only. One block per batch row (16 blocks).
// ---------------------------------------------------------------------------
__global__ __launch_bounds__(256) void k_scan(const int* __restrict__ ws,
                                              int* __restrict__ starts,
                                              int* __restrict__ nwords) {
    __shared__ int wsum[4];
    int b = blockIdx.x;
    int tid = threadIdx.x;
    const int* row = ws + (size_t)b * TT_;
    int vals[8], incl[8];
    int p = 0;
    int t0 = tid * 8;
#pragma unroll
    for (int i = 0; i < 8; ++i) {
        int t = t0 + i;
        int v = (t < TT_) ? row[t] : 0;
        vals[i] = v;
        p += v;
        incl[i] = p;
    }
    int tot = p;
    int lane = tid & 63;
    int x = tot;
#pragma unroll
    for (int off = 1; off < 64; off <<= 1) {
        int v = __shfl_up(x, off);
        if (lane >= off) x += v;
    }
    int wid = tid >> 6;
    if (lane == 63) wsum[wid] = x;
    __syncthreads();
    int wbase = 0;
    for (int q = 0; q < wid; ++q) wbase += wsum[q];
    int excl = wbase + x - tot;
    int* st = starts + (size_t)b * (W_ + 1);
#pragma unroll
    for (int i = 0; i < 8; ++i) {
        if (vals[i]) {
            int w = excl + incl[i] - 1;
            if (w <= W_) st[w] = t0 + i;
        }
    }
    if (tid == 0) {
        int total = wsum[0] + wsum[1] + wsum[2] + wsum[3];
        nwords[b] = total < W_ ? total : W_;
        if (total <= W_) st[total] = TT_;
    }
}

// ---------------------------------------------------------------------------
// K2: heterogeneous bulk kernel. Everything here is mutually independent and
// overlaps the feature stream:
//   [0, G_WF)                 : word feature sums -> bf16 (one block per word)
//   [G_WF, +G_DW)             : dense_w fp32->bf16 (nontemporal src)
//   [.., +G_OW)               : out_w fp32->bf16 into Bcat rows 0..63
//   [.., +G_FOLD)             : W_eff fold -> Bcat rows 64..95 (+ b_eff)
//   [.., +G_ZERO)             : zero out[] (atomic-accumulate target in K3)
// ---------------------------------------------------------------------------
__global__ __launch_bounds__(256) void k_bulk(const float* __restrict__ feat,
                                              const int* __restrict__ starts,
                                              const int* __restrict__ nwords,
                                              const float* __restrict__ dw,
                                              const float* __restrict__ ow,
                                              const float* __restrict__ ob,
                                              const float* __restrict__ bw,
                                              const float* __restrict__ bb,
                                              short* __restrict__ wf,
                                              short* __restrict__ dwb,
                                              short* __restrict__ Bcat,
                                              float* __restrict__ beff,
                                              float* __restrict__ out) {
    __shared__ float smem[NMUT];
    int blk = blockIdx.x;
    int tid = threadIdx.x;

    if (blk < G_WF) {
        // ---- word feature sums ----
        int b = blk / W_;
        int w = blk - b * W_;
        short* outp = wf + (size_t)blk * D_ + tid * 4;
        int nw = nwords[b];
        f32x4 acc = (f32x4){0.f, 0.f, 0.f, 0.f};
        if (w >= nw) {
            acc = (f32x4){1.f, 1.f, 1.f, 1.f};
        } else {
            const int* st = starts + (size_t)b * (W_ + 1);
            int s = st[w], e = st[w + 1];
            const f32x4* base = (const f32x4*)(feat + ((size_t)b * T_ + 1) * D_) + tid;
            for (int t = s; t < e; ++t) {
                f32x4 v = __builtin_nontemporal_load(base + (size_t)t * (D_ / 4));
                acc += v;
            }
        }
        short4 o;
        o.x = f2bf(acc[0]); o.y = f2bf(acc[1]); o.z = f2bf(acc[2]); o.w = f2bf(acc[3]);
        *(short4*)outp = o;
    } else if (blk < G_WF + G_DW) {
        // ---- dense_w cast ----
        int i = (blk - G_WF) * 256 + tid;                 // n4 = 262144
        f32x4 v = __builtin_nontemporal_load((const f32x4*)dw + i);
        short4 o;
        o.x = f2bf(v[0]); o.y = f2bf(v[1]); o.z = f2bf(v[2]); o.w = f2bf(v[3]);
        *(short4*)(dwb + (size_t)i * 4) = o;
    } else if (blk < G_WF + G_DW + G_OW) {
        // ---- out_w cast into Bcat[0:64] ----
        int i = (blk - (G_WF + G_DW)) * 256 + tid;        // n4 = 16384
        f32x4 v = *((const f32x4*)ow + i);
        short4 o;
        o.x = f2bf(v[0]); o.y = f2bf(v[1]); o.z = f2bf(v[2]); o.w = f2bf(v[3]);
        *(short4*)(Bcat + (size_t)i * 4) = o;
    } else if (blk < G_WF + G_DW + G_OW + G_FOLD) {
        // ---- W_eff fold into Bcat[64:96] ----
        int j = blk - (G_WF + G_DW + G_OW);
        if (tid < NMUT) smem[tid] = bw[(size_t)j * (D_ + NMUT) + tid];
        __syncthreads();
        for (int k = tid; k < D_; k += 256) {
            float acc = bw[(size_t)j * (D_ + NMUT) + NMUT + k];
#pragma unroll 8
            for (int c = 0; c < NMUT; ++c)
                acc = fmaf(smem[c], ow[(size_t)c * D_ + k], acc);
            Bcat[(size_t)(NMUT + j) * D_ + k] = f2bf(acc);
        }
        if (tid == 0) {
            float acc = bb[j];
            for (int c = 0; c < NMUT; ++c) acc = fmaf(smem[c], ob[c], acc);
            beff[j] = acc;
        }
    } else {
        // ---- zero the output (K3 accumulates atomically into it) ----
        int i = (blk - (G_WF + G_DW + G_OW + G_FOLD)) * 1024 + tid * 4;
        *(f32x4*)(out + i) = (f32x4){0.f, 0.f, 0.f, 0.f};
    }
}

// ---------------------------------------------------------------------------
// K3: h = tanh(wf . dense_w^T + db) via MFMA (m97 128x128 structure, BK=64),
// then FUSED second GEMM: out += h_tile . Bcat_slice^T (split-N over the 8
// column tiles, f32 atomicAdd; bias added by the bn==0 block only).
// h is never materialized in HBM. C/D layout: col=lane&15, row=(lane>>4)*4+r.
// Htile LDS reuses As/Bs with the G4 XOR swizzle (sidx ^= (row&7)<<3) to
// break the [128][128]-bf16 b128-read bank conflict.
// ---------------------------------------------------------------------------
__global__ __launch_bounds__(256) void k_gemm1(const short* __restrict__ wf,
                                               const short* __restrict__ dwb,
                                               const float* __restrict__ db,
                                               const short* __restrict__ Bcat,
                                               const float* __restrict__ ob,
                                               const float* __restrict__ beff,
                                               float* __restrict__ out) {
    __shared__ short SMEM[16384];              // 32 KB: As[2][4096] | Bs[2][4096]
    short* As = SMEM;
    short* Bs = SMEM + 8192;
    int tid  = threadIdx.x;
    int lane = tid & 63;
    int w    = tid >> 6;
    int wm = w >> 1, wn = w & 1;
    int bm = blockIdx.x * 128;
    int bn = blockIdx.y * 128;

    int ln = lane & 15;
    int qk = lane >> 4;

    int srow = lane >> 2;        // 16 rows per 1KB wave chunk
    int scol = (lane & 3) * 8;   // 4 x 8 bf16 = 32 k per row

    f32x4 acc[4][4];
#pragma unroll
    for (int i = 0; i < 4; ++i)
#pragma unroll
        for (int j = 0; j < 4; ++j) acc[i][j] = (f32x4){0.f, 0.f, 0.f, 0.f};

    for (int kt = 0; kt < D_; kt += 64) {
#pragma unroll
        for (int hh = 0; hh < 2; ++hh) {
#pragma unroll
            for (int p = 0; p < 2; ++p) {
                int chunk = w * 2 + p;               // 0..7, 16 rows each
                int arow = bm + chunk * 16 + srow;
                arow = arow < BW_ ? arow : BW_ - 1;  // clamp tail
                gload_lds16(wf + (size_t)arow * D_ + kt + hh * 32 + scol,
                            &As[hh * 4096 + chunk * 512]);
                int brow = bn + chunk * 16 + srow;
                gload_lds16(dwb + (size_t)brow * D_ + kt + hh * 32 + scol,
                            &Bs[hh * 4096 + chunk * 512]);
            }
        }
        __syncthreads();
#pragma unroll
        for (int hh = 0; hh < 2; ++hh) {
            s8b af[4], bf[4];
#pragma unroll
            for (int i = 0; i < 4; ++i)
                af[i] = *(const s8b*)&As[hh * 4096 + (wm * 64 + i * 16 + ln) * 32 + qk * 8];
#pragma unroll
            for (int j = 0; j < 4; ++j)
                bf[j] = *(const s8b*)&Bs[hh * 4096 + (wn * 64 + j * 16 + ln) * 32 + qk * 8];
#pragma unroll
            for (int i = 0; i < 4; ++i)
#pragma unroll
                for (int j = 0; j < 4; ++j)
                    acc[i][j] = __builtin_amdgcn_mfma_f32_16x16x32_bf16(
                        af[i], bf[j], acc[i][j], 0, 0, 0);
        }
        __syncthreads();
    }

    // ---- tanh + write swizzled 128x128 bf16 h-tile into SMEM ----
    short* Ht = SMEM;
    float bias[4];
#pragma unroll
    for (int j = 0; j < 4; ++j) bias[j] = db[bn + wn * 64 + j * 16 + ln];
#pragma unroll
    for (int i = 0; i < 4; ++i) {
#pragma unroll
        for (int j = 0; j < 4; ++j) {
            int lcol = wn * 64 + j * 16 + ln;
#pragma unroll
            for (int r = 0; r < 4; ++r) {
                int lrow = wm * 64 + i * 16 + qk * 4 + r;
                Ht[(lrow * 128 + lcol) ^ ((lrow & 7) << 3)] =
                    f2bf(fast_tanh(acc[i][j][r] + bias[j]));
            }
        }
    }
    __syncthreads();

    // ---- fused epilogue GEMM: O[128x96] partial = Ht . Bcat[:, bn:bn+128]^T
    // wave w owns rows [w*32, w*32+32); all 96 cols; k = 0..127.
    f32x4 accE[2][6];
#pragma unroll
    for (int i = 0; i < 2; ++i)
#pragma unroll
        for (int cj = 0; cj < 6; ++cj) accE[i][cj] = (f32x4){0.f, 0.f, 0.f, 0.f};

    const short* bp = Bcat + (size_t)ln * D_ + bn + qk * 8;
#pragma unroll
    for (int kk = 0; kk < 4; ++kk) {
        s8b af[2];
#pragma unroll
        for (int i = 0; i < 2; ++i) {
            int row = w * 32 + i * 16 + ln;
            int sc  = kk * 32 + qk * 8;
            af[i] = *(const s8b*)&Ht[(row * 128 + sc) ^ ((row & 7) << 3)];
        }
#pragma unroll
        for (int cj = 0; cj < 6; ++cj) {
            s8b bf = *(const s8b*)(bp + (size_t)cj * 16 * D_ + kk * 32);
#pragma unroll
            for (int i = 0; i < 2; ++i)
                accE[i][cj] = __builtin_amdgcn_mfma_f32_16x16x32_bf16(
                    af[i], bf, accE[i][cj], 0, 0, 0);
        }
    }

    // bias (added exactly once, by the bn==0 block)
    float bj[6];
    bool addb = (blockIdx.y == 0);
#pragma unroll
    for (int cj = 0; cj < 6; ++cj) {
        int c = cj * 16 + ln;
        bj[cj] = addb ? ((c < NMUT) ? ob[c] : beff[c - NMUT]) : 0.f;
    }
#pragma unroll
    for (int i = 0; i < 2; ++i) {
#pragma unroll
        for (int r = 0; r < 4; ++r) {
            int gr = bm + w * 32 + i * 16 + qk * 4 + r;
            if (gr < BW_) {
#pragma unroll
                for (int cj = 0; cj < 6; ++cj) {
                    int c = cj * 16 + ln;
                    float v = accE[i][cj][r] + bj[cj];
                    if (c < NMUT)
                        atomicAdd(&out[(size_t)gr * NMUT + c], v);
                    else
                        atomicAdd(&out[(size_t)BW_ * NMUT + (size_t)gr * NBIN + (c - NMUT)], v);
                }
            }
        }
    }
}

// ---------------------------------------------------------------------------
extern "C" void kernel_launch(void* const* d_in, const int* in_sizes, int n_in,
                              void* d_out, int out_size, void* d_ws, size_t ws_size,
                              hipStream_t stream) {
    const float* feat    = (const float*)d_in[0];
    const int*   wstarts = (const int*)d_in[1];
    const float* dw      = (const float*)d_in[2];
    const float* db      = (const float*)d_in[3];
    const float* ow      = (const float*)d_in[4];
    const float* ob      = (const float*)d_in[5];
    const float* bw      = (const float*)d_in[6];
    const float* bb      = (const float*)d_in[7];
    float* out = (float*)d_out;

    char* ws = (char*)d_ws;
    size_t off = 0;
    auto alloc = [&](size_t bytes) {
        void* p = ws + off;
        off += (bytes + 255) & ~(size_t)255;
        return p;
    };
    short* wf     = (short*)alloc((size_t)BW_ * D_ * 2);
    short* dwb    = (short*)alloc((size_t)D_ * D_ * 2);
    short* Bcat   = (short*)alloc((size_t)(NMUT + NBIN) * D_ * 2);
    float* beff   = (float*)alloc(NBIN * 4);
    int*   starts = (int*)alloc((size_t)B_ * (W_ + 1) * 4);
    int*   nwords = (int*)alloc(B_ * 4);

    k_scan<<<16, 256, 0, stream>>>(wstarts, starts, nwords);
    k_bulk<<<G_WF + G_DW + G_OW + G_FOLD + G_ZERO, 256, 0, stream>>>(
        feat, starts, nwords, dw, ow, ob, bw, bb, wf, dwb, Bcat, beff, out);
    k_gemm1<<<dim3((BW_ + 127) / 128, D_ / 128), 256, 0, stream>>>(
        wf, dwb, db, Bcat, ob, beff, out);
}

// Round 2
// 270.879 us; speedup vs baseline: 1.0656x; 1.0656x over previous
//
#include <hip/hip_runtime.h>
#include <stdint.h>

#define B_   16
#define T_   2048
#define D_   1024
#define TT_  2046
#define W_   682            // MAX_WORDS
#define BW_  (B_ * W_)      // 10912
#define NMUT 64
#define NBIN 32

// K2 heterogeneous-grid section sizes
#define G_WF   BW_          // word-feature blocks
#define G_DW   1024         // dense_w cast blocks (1024*1024 f32 / (256*4))
#define G_OW   64           // out_w cast blocks
#define G_FOLD 32           // W_eff fold blocks

typedef __attribute__((ext_vector_type(8))) short s8b;    // 8 bf16 (4 VGPRs)
typedef __attribute__((ext_vector_type(4))) float f32x4;

__device__ inline short f2bf(float f) {                   // RNE f32->bf16
    uint32_t u = __builtin_bit_cast(uint32_t, f);
    u += 0x7FFFu + ((u >> 16) & 1u);
    return (short)(u >> 16);
}

__device__ inline float fast_tanh(float x) {
    float xc = fminf(fmaxf(x, -15.f), 15.f);
    float e  = __expf(2.f * xc);
    return 1.f - 2.f / (e + 1.f);
}

__device__ inline void gload_lds16(const void* g, void* l) {
    __builtin_amdgcn_global_load_lds(
        (const __attribute__((address_space(1))) uint32_t*)g,
        (__attribute__((address_space(3))) uint32_t*)l, 16, 0, 0);
}

// ---------------------------------------------------------------------------
// K1: word-boundary scan only. One block per batch row (16 blocks).
// ---------------------------------------------------------------------------
__global__ __launch_bounds__(256) void k_scan(const int* __restrict__ ws,
                                              int* __restrict__ starts,
                                              int* __restrict__ nwords) {
    __shared__ int wsum[4];
    int b = blockIdx.x;
    int tid = threadIdx.x;
    const int* row = ws + (size_t)b * TT_;
    int vals[8], incl[8];
    int p = 0;
    int t0 = tid * 8;
#pragma unroll
    for (int i = 0; i < 8; ++i) {
        int t = t0 + i;
        int v = (t < TT_) ? row[t] : 0;
        vals[i] = v;
        p += v;
        incl[i] = p;
    }
    int tot = p;
    int lane = tid & 63;
    int x = tot;
#pragma unroll
    for (int off = 1; off < 64; off <<= 1) {
        int v = __shfl_up(x, off);
        if (lane >= off) x += v;
    }
    int wid = tid >> 6;
    if (lane == 63) wsum[wid] = x;
    __syncthreads();
    int wbase = 0;
    for (int q = 0; q < wid; ++q) wbase += wsum[q];
    int excl = wbase + x - tot;
    int* st = starts + (size_t)b * (W_ + 1);
#pragma unroll
    for (int i = 0; i < 8; ++i) {
        if (vals[i]) {
            int w = excl + incl[i] - 1;
            if (w <= W_) st[w] = t0 + i;
        }
    }
    if (tid == 0) {
        int total = wsum[0] + wsum[1] + wsum[2] + wsum[3];
        nwords[b] = total < W_ ? total : W_;
        if (total <= W_) st[total] = TT_;
    }
}

// ---------------------------------------------------------------------------
// K2: heterogeneous bulk kernel. Everything here is mutually independent and
// overlaps the feature stream:
//   [0, G_WF)                 : word feature sums -> bf16 (one block per word)
//   [G_WF, +G_DW)             : dense_w fp32->bf16 (nontemporal src)
//   [.., +G_OW)               : out_w fp32->bf16 into Bcat rows 0..63
//   [.., +G_FOLD)             : W_eff fold -> Bcat rows 64..95 (+ b_eff)
// ---------------------------------------------------------------------------
__global__ __launch_bounds__(256) void k_bulk(const float* __restrict__ feat,
                                              const int* __restrict__ starts,
                                              const int* __restrict__ nwords,
                                              const float* __restrict__ dw,
                                              const float* __restrict__ ow,
                                              const float* __restrict__ ob,
                                              const float* __restrict__ bw,
                                              const float* __restrict__ bb,
                                              short* __restrict__ wf,
                                              short* __restrict__ dwb,
                                              short* __restrict__ Bcat,
                                              float* __restrict__ beff) {
    __shared__ float smem[NMUT];
    int blk = blockIdx.x;
    int tid = threadIdx.x;

    if (blk < G_WF) {
        // ---- word feature sums ----
        int b = blk / W_;
        int w = blk - b * W_;
        short* outp = wf + (size_t)blk * D_ + tid * 4;
        int nw = nwords[b];
        f32x4 acc = (f32x4){0.f, 0.f, 0.f, 0.f};
        if (w >= nw) {
            acc = (f32x4){1.f, 1.f, 1.f, 1.f};
        } else {
            const int* st = starts + (size_t)b * (W_ + 1);
            int s = st[w], e = st[w + 1];
            const f32x4* base = (const f32x4*)(feat + ((size_t)b * T_ + 1) * D_) + tid;
            for (int t = s; t < e; ++t) {
                f32x4 v = __builtin_nontemporal_load(base + (size_t)t * (D_ / 4));
                acc += v;
            }
        }
        short4 o;
        o.x = f2bf(acc[0]); o.y = f2bf(acc[1]); o.z = f2bf(acc[2]); o.w = f2bf(acc[3]);
        *(short4*)outp = o;
    } else if (blk < G_WF + G_DW) {
        // ---- dense_w cast ----
        int i = (blk - G_WF) * 256 + tid;                 // n4 = 262144
        f32x4 v = __builtin_nontemporal_load((const f32x4*)dw + i);
        short4 o;
        o.x = f2bf(v[0]); o.y = f2bf(v[1]); o.z = f2bf(v[2]); o.w = f2bf(v[3]);
        *(short4*)(dwb + (size_t)i * 4) = o;
    } else if (blk < G_WF + G_DW + G_OW) {
        // ---- out_w cast into Bcat[0:64] ----
        int i = (blk - (G_WF + G_DW)) * 256 + tid;        // n4 = 16384
        f32x4 v = *((const f32x4*)ow + i);
        short4 o;
        o.x = f2bf(v[0]); o.y = f2bf(v[1]); o.z = f2bf(v[2]); o.w = f2bf(v[3]);
        *(short4*)(Bcat + (size_t)i * 4) = o;
    } else {
        // ---- W_eff fold into Bcat[64:96] ----
        int j = blk - (G_WF + G_DW + G_OW);
        if (tid < NMUT) smem[tid] = bw[(size_t)j * (D_ + NMUT) + tid];
        __syncthreads();
        for (int k = tid; k < D_; k += 256) {
            float acc = bw[(size_t)j * (D_ + NMUT) + NMUT + k];
#pragma unroll 8
            for (int c = 0; c < NMUT; ++c)
                acc = fmaf(smem[c], ow[(size_t)c * D_ + k], acc);
            Bcat[(size_t)(NMUT + j) * D_ + k] = f2bf(acc);
        }
        if (tid == 0) {
            float acc = bb[j];
            for (int c = 0; c < NMUT; ++c) acc = fmaf(smem[c], ob[c], acc);
            beff[j] = acc;
        }
    }
}

// ---------------------------------------------------------------------------
// K3: h = tanh(wf . dense_w^T + db) via MFMA bf16 (m97 128x128 structure,
// BK=64 as two 32-k sub-buffers). C/D layout: col=lane&15, row=(lane>>4)*4+r.
// h written bf16 to HBM (L3-resident for K4).
// ---------------------------------------------------------------------------
__global__ __launch_bounds__(256) void k_gemm1(const short* __restrict__ wf,
                                               const short* __restrict__ dwb,
                                               const float* __restrict__ db,
                                               short* __restrict__ h) {
    __shared__ short As[2][128 * 32];
    __shared__ short Bs[2][128 * 32];
    int tid  = threadIdx.x;
    int lane = tid & 63;
    int w    = tid >> 6;
    int wm = w >> 1, wn = w & 1;
    int bm = blockIdx.x * 128;
    int bn = blockIdx.y * 128;

    int ln = lane & 15;
    int qk = lane >> 4;

    int srow = lane >> 2;        // 16 rows per 1KB wave chunk
    int scol = (lane & 3) * 8;   // 4 x 8 bf16 = 32 k per row

    f32x4 acc[4][4];
#pragma unroll
    for (int i = 0; i < 4; ++i)
#pragma unroll
        for (int j = 0; j < 4; ++j) acc[i][j] = (f32x4){0.f, 0.f, 0.f, 0.f};

    for (int kt = 0; kt < D_; kt += 64) {
#pragma unroll
        for (int hh = 0; hh < 2; ++hh) {
#pragma unroll
            for (int p = 0; p < 2; ++p) {
                int chunk = w * 2 + p;               // 0..7, 16 rows each
                int arow = bm + chunk * 16 + srow;
                arow = arow < BW_ ? arow : BW_ - 1;  // clamp tail
                gload_lds16(wf + (size_t)arow * D_ + kt + hh * 32 + scol,
                            &As[hh][chunk * 512]);
                int brow = bn + chunk * 16 + srow;
                gload_lds16(dwb + (size_t)brow * D_ + kt + hh * 32 + scol,
                            &Bs[hh][chunk * 512]);
            }
        }
        __syncthreads();
#pragma unroll
        for (int hh = 0; hh < 2; ++hh) {
            s8b af[4], bf[4];
#pragma unroll
            for (int i = 0; i < 4; ++i)
                af[i] = *(const s8b*)&As[hh][(wm * 64 + i * 16 + ln) * 32 + qk * 8];
#pragma unroll
            for (int j = 0; j < 4; ++j)
                bf[j] = *(const s8b*)&Bs[hh][(wn * 64 + j * 16 + ln) * 32 + qk * 8];
#pragma unroll
            for (int i = 0; i < 4; ++i)
#pragma unroll
                for (int j = 0; j < 4; ++j)
                    acc[i][j] = __builtin_amdgcn_mfma_f32_16x16x32_bf16(
                        af[i], bf[j], acc[i][j], 0, 0, 0);
        }
        __syncthreads();
    }

    float bias[4];
#pragma unroll
    for (int j = 0; j < 4; ++j) bias[j] = db[bn + wn * 64 + j * 16 + ln];
#pragma unroll
    for (int i = 0; i < 4; ++i) {
        int row0 = bm + wm * 64 + i * 16 + qk * 4;
#pragma unroll
        for (int r = 0; r < 4; ++r) {
            int row = row0 + r;
            if (row < BW_) {
#pragma unroll
                for (int j = 0; j < 4; ++j) {
                    int cn = bn + wn * 64 + j * 16 + ln;
                    h[(size_t)row * D_ + cn] =
                        f2bf(fast_tanh(acc[i][j][r] + bias[j]));
                }
            }
        }
    }
}

// ---------------------------------------------------------------------------
// K4: [wcl | bin] = h . Bcat^T + bias via MFMA, K-split for occupancy.
// 682 blocks (one per 16 output rows, 2.7 blocks/CU); 4 waves each own a
// K-quarter (256) -> 48 MFMA/wave; 24KB LDS cross-wave reduce; plain stores.
// ---------------------------------------------------------------------------
__global__ __launch_bounds__(256) void k_gemm2(const short* __restrict__ h,
                                               const short* __restrict__ Bcat,
                                               const float* __restrict__ ob,
                                               const float* __restrict__ beff,
                                               float* __restrict__ out) {
    __shared__ float red[4][6][256];           // [wave][cj][lane*4+r]
    int tid  = threadIdx.x;
    int lane = tid & 63;
    int w    = tid >> 6;
    int ln = lane & 15, qk = lane >> 4;
    int m0 = blockIdx.x * 16;                  // BW_ = 682*16 exactly

    const short* ap = h    + (size_t)(m0 + ln) * D_ + w * 256 + qk * 8;
    const short* bp = Bcat + (size_t)ln        * D_ + w * 256 + qk * 8;

    f32x4 acc[6];
#pragma unroll
    for (int cj = 0; cj < 6; ++cj) acc[cj] = (f32x4){0.f, 0.f, 0.f, 0.f};

#pragma unroll
    for (int kk = 0; kk < 8; ++kk) {           // 8 x 32 = 256 K per wave
        s8b af = *(const s8b*)(ap + kk * 32);
#pragma unroll
        for (int cj = 0; cj < 6; ++cj) {
            s8b bf = *(const s8b*)(bp + (size_t)cj * 16 * D_ + kk * 32);
            acc[cj] = __builtin_amdgcn_mfma_f32_16x16x32_bf16(af, bf, acc[cj], 0, 0, 0);
        }
    }

#pragma unroll
    for (int cj = 0; cj < 6; ++cj)
        *(f32x4*)&red[w][cj][lane * 4] = acc[cj];
    __syncthreads();

    // 1536 outputs; 256 threads x 6. acc[cj][r]: row = qk*4+r, col = cj*16+ln.
#pragma unroll
    for (int i = tid; i < 1536; i += 256) {
        int cj = i >> 8;
        int e  = i & 255;                      // lane*4 + r
        float v = red[0][cj][e] + red[1][cj][e] + red[2][cj][e] + red[3][cj][e];
        int l = e >> 2, r = e & 3;
        int row = m0 + (l >> 4) * 4 + r;
        int c   = cj * 16 + (l & 15);
        v += (c < NMUT) ? ob[c] : beff[c - NMUT];
        if (c < NMUT) out[(size_t)row * NMUT + c] = v;
        else out[(size_t)BW_ * NMUT + (size_t)row * NBIN + (c - NMUT)] = v;
    }
}

// ---------------------------------------------------------------------------
extern "C" void kernel_launch(void* const* d_in, const int* in_sizes, int n_in,
                              void* d_out, int out_size, void* d_ws, size_t ws_size,
                              hipStream_t stream) {
    const float* feat    = (const float*)d_in[0];
    const int*   wstarts = (const int*)d_in[1];
    const float* dw      = (const float*)d_in[2];
    const float* db      = (const float*)d_in[3];
    const float* ow      = (const float*)d_in[4];
    const float* ob      = (const float*)d_in[5];
    const float* bw      = (const float*)d_in[6];
    const float* bb      = (const float*)d_in[7];
    float* out = (float*)d_out;

    char* ws = (char*)d_ws;
    size_t off = 0;
    auto alloc = [&](size_t bytes) {
        void* p = ws + off;
        off += (bytes + 255) & ~(size_t)255;
        return p;
    };
    short* wf     = (short*)alloc((size_t)BW_ * D_ * 2);
    short* h      = (short*)alloc((size_t)BW_ * D_ * 2);
    short* dwb    = (short*)alloc((size_t)D_ * D_ * 2);
    short* Bcat   = (short*)alloc((size_t)(NMUT + NBIN) * D_ * 2);
    float* beff   = (float*)alloc(NBIN * 4);
    int*   starts = (int*)alloc((size_t)B_ * (W_ + 1) * 4);
    int*   nwords = (int*)alloc(B_ * 4);

    k_scan<<<16, 256, 0, stream>>>(wstarts, starts, nwords);
    k_bulk<<<G_WF + G_DW + G_OW + G_FOLD, 256, 0, stream>>>(
        feat, starts, nwords, dw, ow, ob, bw, bb, wf, dwb, Bcat, beff);
    k_gemm1<<<dim3((BW_ + 127) / 128, D_ / 128), 256, 0, stream>>>(wf, dwb, db, h);
    k_gemm2<<<BW_ / 16, 256, 0, stream>>>(h, Bcat, ob, beff, out);
}